// Round 4
// baseline (117.311 us; speedup 1.0000x reference)
//
#include <hip/hip_runtime.h>
#include <hip/hip_bf16.h>
#include <cstdint>

#define DT_F    0.01f
#define NB      16      // batch
#define T_SEQ   2048    // sequence
#define DD      1024    // d_in
#define NS      128     // n_state
#define CHUNK   32      // scan chunk length
#define NCH     64      // chunks = T_SEQ/CHUNK

using f32x4  = __attribute__((ext_vector_type(4))) float;
using bf16x8 = __attribute__((ext_vector_type(8))) short;
using fl4    = __attribute__((ext_vector_type(4))) float;

#define AS1(p) ((const __attribute__((address_space(1))) void*)(p))
#define AS3(p) ((__attribute__((address_space(3))) void*)(p))

__device__ __forceinline__ unsigned short f2bf(float f) {
  union { float f; unsigned u; } v; v.f = f;
  unsigned r = v.u + 0x7fffu + ((v.u >> 16) & 1u);   // RNE
  return (unsigned short)(r >> 16);
}
__device__ __forceinline__ float bf2f(unsigned short s) {
  union { unsigned u; float f; } v; v.u = ((unsigned)s) << 16;
  return v.f;
}
__device__ __forceinline__ unsigned short f2bf_hw(float f) {
  __hip_bfloat16 h = __float2bfloat16(f);            // RNE, compiler emits v_cvt_pk
  return __builtin_bit_cast(unsigned short, h);
}

// ---------------------------------------------------------------------------
// prep_all: blocks 0..511 convert C->bf16; blocks 512..639 build a_disc+B_disc.
// ---------------------------------------------------------------------------
__global__ void prep_all(const float* __restrict__ Ar, const float* __restrict__ Ai,
                         const float* __restrict__ B, const float* __restrict__ C,
                         unsigned short* __restrict__ W, unsigned short* __restrict__ Cb,
                         float* __restrict__ ad) {
  const int blk = blockIdx.x;
  const int tid = threadIdx.x;
  if (blk < 512) {
    const int i = blk * 256 + tid;
    Cb[i] = f2bf(C[i]);
    return;
  }
  const int n = blk - 512;
  const float ar = Ar[n], ai = Ai[n];
  const float dr = 1.f - 0.5f * DT_F * ar;
  const float di = -0.5f * DT_F * ai;
  const float inv = 1.f / (dr * dr + di * di);
  const float nr = 1.f + 0.5f * DT_F * ar;
  const float ni = 0.5f * DT_F * ai;
  if (tid == 0) {
    ad[n]      = (nr * dr + ni * di) * inv;   // Re(a_disc)
    ad[NS + n] = (ni * dr - nr * di) * inv;   // Im(a_disc)
  }
  const float s  = sqrtf(DT_F);
  const float cr = s * dr * inv;
  const float ci = -s * di * inv;
  for (int d = tid; d < DD; d += 256) {
    const float b = B[(size_t)n * DD + d];
    W[(size_t)n * DD + d]        = f2bf(b * cr);
    W[(size_t)(NS + n) * DD + d] = f2bf(b * ci);
  }
}

// ---------------------------------------------------------------------------
// gemm1: Bu[M=32768 x 256] (bf16) = cvt_bf16(u[M x 1024]) * W[256 x 1024]^T
// 128x128 tile, 4 waves (2x2 of 64x64), BK=64, 16 K-steps.
// Pipelined: Bs double-buffered via global_load_lds; A f32 prefetched to regs
// for t+1 during MFMA of t; raw s_barrier between MFMA and As overwrite.
// ---------------------------------------------------------------------------
__global__ __launch_bounds__(256, 2) void gemm1(const float* __restrict__ U,
                                                const unsigned short* __restrict__ Bw,
                                                unsigned short* __restrict__ Bu) {
  __shared__ __align__(16) unsigned short As[128 * 64];
  __shared__ __align__(16) unsigned short Bs[2][128 * 64];
  const int tid  = threadIdx.x;
  const int lane = tid & 63;
  const int wave = tid >> 6;

  const int L   = blockIdx.x;          // 512 blocks, XCD-chunked
  const int xcd = L & 7;
  const int k   = L >> 3;              // 0..63 per XCD
  const int bm  = xcd * 32 + (k >> 1);
  const int bn  = k & 1;
  const int rowA0 = bm * 128, colB0 = bn * 128;
  const int wm = (wave >> 1) * 64, wn = (wave & 1) * 64;

  f32x4 acc[4][4];
  const f32x4 zero = {0.f, 0.f, 0.f, 0.f};
#pragma unroll
  for (int i = 0; i < 4; ++i)
#pragma unroll
    for (int j = 0; j < 4; ++j) acc[i][j] = zero;

  const int srow = tid >> 3;           // 0..31
  const int scol = (tid & 7) * 8;      // 0..56
  const int grow = wave * 8 + (lane >> 3);       // glds row within 32-row group
  const int gcol = (lane & 7) * 8;

  fl4 a0[4], a1[4];                    // A prefetch regs (t+1)

  // ---- prologue: stage tile 0 ----
#pragma unroll
  for (int it = 0; it < 4; ++it) {
    const unsigned short* gb = Bw + (size_t)(colB0 + it * 32 + grow) * DD + gcol;
    __builtin_amdgcn_global_load_lds(AS1(gb), AS3(&Bs[0][(it * 32 + wave * 8) * 64]), 16, 0, 0);
  }
#pragma unroll
  for (int it = 0; it < 4; ++it) {
    const float* ga = U + (size_t)(rowA0 + it * 32 + srow) * DD + scol;
    a0[it] = *(const fl4*)ga;
    a1[it] = *(const fl4*)(ga + 4);
  }
#pragma unroll
  for (int it = 0; it < 4; ++it) {
    bf16x8 pk;
#pragma unroll
    for (int e = 0; e < 4; ++e) { pk[e] = (short)f2bf_hw(a0[it][e]); pk[4 + e] = (short)f2bf_hw(a1[it][e]); }
    *(bf16x8*)&As[(it * 32 + srow) * 64 + scol] = pk;
  }
  __syncthreads();

  // ---- main loop: compute t, stage t+1 ----
  for (int t = 0; t < 15; ++t) {
    const int cur = t & 1, nxt = cur ^ 1;
    const int k1 = (t + 1) * 64;
    // issue next-tile loads first (stay in flight through the MFMAs)
#pragma unroll
    for (int it = 0; it < 4; ++it) {
      const unsigned short* gb = Bw + (size_t)(colB0 + it * 32 + grow) * DD + k1 + gcol;
      __builtin_amdgcn_global_load_lds(AS1(gb), AS3(&Bs[nxt][(it * 32 + wave * 8) * 64]), 16, 0, 0);
    }
#pragma unroll
    for (int it = 0; it < 4; ++it) {
      const float* ga = U + (size_t)(rowA0 + it * 32 + srow) * DD + k1 + scol;
      a0[it] = *(const fl4*)ga;
      a1[it] = *(const fl4*)(ga + 4);
    }
    // compute current tile
#pragma unroll
    for (int ks = 0; ks < 2; ++ks) {
      bf16x8 af[4], bfr[4];
#pragma unroll
      for (int i = 0; i < 4; ++i)
        af[i] = *(const bf16x8*)&As[(wm + i * 16 + (lane & 15)) * 64 + ks * 32 + (lane >> 4) * 8];
#pragma unroll
      for (int j = 0; j < 4; ++j)
        bfr[j] = *(const bf16x8*)&Bs[cur][(wn + j * 16 + (lane & 15)) * 64 + ks * 32 + (lane >> 4) * 8];
#pragma unroll
      for (int i = 0; i < 4; ++i)
#pragma unroll
        for (int j = 0; j < 4; ++j)
          acc[i][j] = __builtin_amdgcn_mfma_f32_16x16x32_bf16(af[i], bfr[j], acc[i][j], 0, 0, 0);
    }
    // all waves past their MFMA issue -> As VGPR sources consumed; safe to overwrite
    __builtin_amdgcn_s_barrier();
#pragma unroll
    for (int it = 0; it < 4; ++it) {
      bf16x8 pk;
#pragma unroll
      for (int e = 0; e < 4; ++e) { pk[e] = (short)f2bf_hw(a0[it][e]); pk[4 + e] = (short)f2bf_hw(a1[it][e]); }
      *(bf16x8*)&As[(it * 32 + srow) * 64 + scol] = pk;
    }
    __syncthreads();   // drains vmcnt (Bs[nxt] glds) + lgkm (As writes)
  }

  // ---- last tile (t=15, cur=1) ----
#pragma unroll
  for (int ks = 0; ks < 2; ++ks) {
    bf16x8 af[4], bfr[4];
#pragma unroll
    for (int i = 0; i < 4; ++i)
      af[i] = *(const bf16x8*)&As[(wm + i * 16 + (lane & 15)) * 64 + ks * 32 + (lane >> 4) * 8];
#pragma unroll
    for (int j = 0; j < 4; ++j)
      bfr[j] = *(const bf16x8*)&Bs[1][(wn + j * 16 + (lane & 15)) * 64 + ks * 32 + (lane >> 4) * 8];
#pragma unroll
    for (int i = 0; i < 4; ++i)
#pragma unroll
      for (int j = 0; j < 4; ++j)
        acc[i][j] = __builtin_amdgcn_mfma_f32_16x16x32_bf16(af[i], bfr[j], acc[i][j], 0, 0, 0);
  }

  // C/D layout: col = lane&15, row = (lane>>4)*4 + q
#pragma unroll
  for (int i = 0; i < 4; ++i) {
    const int r0 = rowA0 + wm + i * 16 + (lane >> 4) * 4;
#pragma unroll
    for (int j = 0; j < 4; ++j) {
      const int c = colB0 + wn + j * 16 + (lane & 15);
#pragma unroll
      for (int q = 0; q < 4; ++q)
        Bu[(size_t)(r0 + q) * 256 + c] = f2bf(acc[i][j][q]);
    }
  }
}

// ---------------------------------------------------------------------------
// gemm2: y[M=32768 x 1024] (f32) = Hs[M x 128] * Cb[1024 x 128]^T
// Single-shot K=128: stage full 128x128 tiles of A and B once (glds),
// one barrier pair, 64 MFMA/wave, store.
// ---------------------------------------------------------------------------
__global__ __launch_bounds__(256, 2) void gemm2(const unsigned short* __restrict__ Hs,
                                                const unsigned short* __restrict__ Cb,
                                                float* __restrict__ y) {
  __shared__ __align__(16) unsigned short As[128 * 128];
  __shared__ __align__(16) unsigned short Bs[128 * 128];
  const int tid  = threadIdx.x;
  const int lane = tid & 63;
  const int wave = tid >> 6;

  const int L   = blockIdx.x;          // 2048 blocks, XCD-chunked
  const int xcd = L & 7;
  const int k   = L >> 3;              // 0..255 per XCD
  const int bm  = xcd * 32 + (k >> 3);
  const int bn  = k & 7;
  const int rowA0 = bm * 128, colB0 = bn * 128;
  const int wm = (wave >> 1) * 64, wn = (wave & 1) * 64;

  // stage: rows of 128 cols (256 B); one glds covers 4 rows (64 lanes x 16 B)
  const int g4row = lane >> 4;                 // 0..3
  const int g4col = (lane & 15) * 8;           // 0..120
#pragma unroll
  for (int it = 0; it < 8; ++it) {
    const int r = wave * 32 + it * 4;
    const unsigned short* ga = Hs + (size_t)(rowA0 + r + g4row) * NS + g4col;
    __builtin_amdgcn_global_load_lds(AS1(ga), AS3(&As[r * 128]), 16, 0, 0);
  }
#pragma unroll
  for (int it = 0; it < 8; ++it) {
    const int r = wave * 32 + it * 4;
    const unsigned short* gb = Cb + (size_t)(colB0 + r + g4row) * NS + g4col;
    __builtin_amdgcn_global_load_lds(AS1(gb), AS3(&Bs[r * 128]), 16, 0, 0);
  }
  __syncthreads();

  f32x4 acc[4][4];
  const f32x4 zero = {0.f, 0.f, 0.f, 0.f};
#pragma unroll
  for (int i = 0; i < 4; ++i)
#pragma unroll
    for (int j = 0; j < 4; ++j) acc[i][j] = zero;

#pragma unroll
  for (int ks = 0; ks < 4; ++ks) {
    bf16x8 af[4], bfr[4];
#pragma unroll
    for (int i = 0; i < 4; ++i)
      af[i] = *(const bf16x8*)&As[(wm + i * 16 + (lane & 15)) * 128 + ks * 32 + (lane >> 4) * 8];
#pragma unroll
    for (int j = 0; j < 4; ++j)
      bfr[j] = *(const bf16x8*)&Bs[(wn + j * 16 + (lane & 15)) * 128 + ks * 32 + (lane >> 4) * 8];
#pragma unroll
    for (int i = 0; i < 4; ++i)
#pragma unroll
      for (int j = 0; j < 4; ++j)
        acc[i][j] = __builtin_amdgcn_mfma_f32_16x16x32_bf16(af[i], bfr[j], acc[i][j], 0, 0, 0);
  }

#pragma unroll
  for (int i = 0; i < 4; ++i) {
    const int r0 = rowA0 + wm + i * 16 + (lane >> 4) * 4;
#pragma unroll
    for (int j = 0; j < 4; ++j) {
      const int c = colB0 + wn + j * 16 + (lane & 15);
#pragma unroll
      for (int q = 0; q < 4; ++q)
        y[(size_t)(r0 + q) * DD + c] = acc[i][j][q];
    }
  }
}

// ---------------------------------------------------------------------------
// scan_finals: per (b, chunk) local complex scan (h0=0) over bf16 Bu;
// writes chunk-final h (f32) to F. grid (NCH, NB), 128 threads.
// ---------------------------------------------------------------------------
__global__ void scan_finals(const unsigned short* __restrict__ Bu,
                            const float* __restrict__ ad, float* __restrict__ F) {
  const int c = blockIdx.x, b = blockIdx.y;
  const int n = threadIdx.x;
  const float ar = ad[n], ai = ad[NS + n];
  float hr = 0.f, hi = 0.f;
  const unsigned short* p = Bu + ((size_t)b * T_SEQ + (size_t)c * CHUNK) * 256;
#pragma unroll 8
  for (int t = 0; t < CHUNK; ++t) {
    const float br = bf2f(p[t * 256 + n]);
    const float bi = bf2f(p[t * 256 + 128 + n]);
    const float nr = fmaf(ar, hr, fmaf(-ai, hi, br));
    const float ni = fmaf(ar, hi, fmaf(ai, hr, bi));
    hr = nr; hi = ni;
  }
  F[((size_t)b * NCH + c) * 256 + n]       = hr;
  F[((size_t)b * NCH + c) * 256 + 128 + n] = hi;
}

// ---------------------------------------------------------------------------
// scan_apply: fold predecessor finals into carry (aL = a^CHUNK), seed h,
// re-run recurrence from Bu, emit Re(h) bf16 -> Hs.
// ---------------------------------------------------------------------------
__global__ void scan_apply(const unsigned short* __restrict__ Bu,
                           const float* __restrict__ F, const float* __restrict__ ad,
                           unsigned short* __restrict__ Hs) {
  const int c = blockIdx.x, b = blockIdx.y;
  const int n = threadIdx.x;
  const float ar = ad[n], ai = ad[NS + n];
  float alr = ar, ali = ai;                 // a^CHUNK, log2(32)=5 squarings
#pragma unroll
  for (int s = 0; s < 5; ++s) {
    const float tr = alr * alr - ali * ali;
    const float ti = 2.f * alr * ali;
    alr = tr; ali = ti;
  }
  float hr = 0.f, hi = 0.f;                 // carry = h at end of chunk c-1
  for (int cc = 0; cc < c; ++cc) {
    const float fr = F[((size_t)b * NCH + cc) * 256 + n];
    const float fi = F[((size_t)b * NCH + cc) * 256 + 128 + n];
    const float nr = fmaf(alr, hr, fmaf(-ali, hi, fr));
    const float ni = fmaf(alr, hi, fmaf(ali, hr, fi));
    hr = nr; hi = ni;
  }
  const unsigned short* p = Bu + ((size_t)b * T_SEQ + (size_t)c * CHUNK) * 256;
  unsigned short* o = Hs + ((size_t)b * T_SEQ + (size_t)c * CHUNK) * 128;
#pragma unroll 8
  for (int t = 0; t < CHUNK; ++t) {
    const float br = bf2f(p[t * 256 + n]);
    const float bi = bf2f(p[t * 256 + 128 + n]);
    const float nr = fmaf(ar, hr, fmaf(-ai, hi, br));
    const float ni = fmaf(ar, hi, fmaf(ai, hr, bi));
    hr = nr; hi = ni;
    o[t * 128 + n] = f2bf(hr);
  }
}

// ---------------------------------------------------------------------------
extern "C" void kernel_launch(void* const* d_in, const int* in_sizes, int n_in,
                              void* d_out, int out_size, void* d_ws, size_t ws_size,
                              hipStream_t stream) {
  const float* u  = (const float*)d_in[0];
  const float* Ar = (const float*)d_in[1];
  const float* Ai = (const float*)d_in[2];
  const float* B  = (const float*)d_in[3];
  const float* C  = (const float*)d_in[4];
  float* y = (float*)d_out;
  char* ws = (char*)d_ws;

  // workspace layout (~27.3 MB)
  unsigned short* W  = (unsigned short*)(ws);                                // 512 KB (B_disc bf16)
  unsigned short* Cb = (unsigned short*)(ws + (512 << 10));                  // 256 KB (C bf16)
  float*          ad = (float*)(ws + (768 << 10));                           // 1 KB   (a_disc)
  unsigned short* Bu = (unsigned short*)(ws + (1 << 20));                    // 16.75 MB (complex bf16 Bu)
  unsigned short* Hs = (unsigned short*)(ws + (1 << 20) + 16777216);         // 8 MB   (Re(h) bf16)
  float*          F  = (float*)(ws + (1 << 20) + 16777216 + 8388608);        // 1 MB   (chunk finals f32)

  prep_all<<<dim3(640), dim3(256), 0, stream>>>(Ar, Ai, B, C, W, Cb, ad);
  gemm1<<<dim3(512), dim3(256), 0, stream>>>(u, W, Bu);
  scan_finals<<<dim3(NCH, NB), dim3(128), 0, stream>>>(Bu, ad, F);
  scan_apply <<<dim3(NCH, NB), dim3(128), 0, stream>>>(Bu, F, ad, Hs);
  gemm2<<<dim3(2048), dim3(256), 0, stream>>>(Hs, Cb, y);
}

// Round 5
// 89.915 us; speedup vs baseline: 1.3047x; 1.3047x over previous
//
#include <hip/hip_runtime.h>
#include <hip/hip_bf16.h>
#include <cstdint>

#define DT_F    0.01f
#define NB      16      // batch
#define T_SEQ   2048    // sequence
#define DD      1024    // d_in
#define NS      128     // n_state
#define CHUNK   64      // scan chunk length
#define NCH     32      // chunks = T_SEQ/CHUNK

using f32x4  = __attribute__((ext_vector_type(4))) float;
using bf16x8 = __attribute__((ext_vector_type(8))) short;
using fl4    = __attribute__((ext_vector_type(4))) float;

#define AS1(p) ((const __attribute__((address_space(1))) void*)(p))
#define AS3(p) ((__attribute__((address_space(3))) void*)(p))

__device__ __forceinline__ unsigned short f2bf(float f) {
  union { float f; unsigned u; } v; v.f = f;
  unsigned r = v.u + 0x7fffu + ((v.u >> 16) & 1u);   // RNE
  return (unsigned short)(r >> 16);
}
__device__ __forceinline__ float bf2f(unsigned short s) {
  union { unsigned u; float f; } v; v.u = ((unsigned)s) << 16;
  return v.f;
}
__device__ __forceinline__ unsigned short f2bf_hw(float f) {
  __hip_bfloat16 h = __float2bfloat16(f);            // RNE, maps to v_cvt
  return __builtin_bit_cast(unsigned short, h);
}

// ---------------------------------------------------------------------------
// prep_all: blocks 0..511 convert C->bf16; blocks 512..639 build a_disc+B_disc.
// ---------------------------------------------------------------------------
__global__ void prep_all(const float* __restrict__ Ar, const float* __restrict__ Ai,
                         const float* __restrict__ B, const float* __restrict__ C,
                         unsigned short* __restrict__ W, unsigned short* __restrict__ Cb,
                         float* __restrict__ ad) {
  const int blk = blockIdx.x;
  const int tid = threadIdx.x;
  if (blk < 512) {
    const int i = blk * 256 + tid;
    Cb[i] = f2bf(C[i]);
    return;
  }
  const int n = blk - 512;
  const float ar = Ar[n], ai = Ai[n];
  const float dr = 1.f - 0.5f * DT_F * ar;
  const float di = -0.5f * DT_F * ai;
  const float inv = 1.f / (dr * dr + di * di);
  const float nr = 1.f + 0.5f * DT_F * ar;
  const float ni = 0.5f * DT_F * ai;
  if (tid == 0) {
    ad[n]      = (nr * dr + ni * di) * inv;   // Re(a_disc)
    ad[NS + n] = (ni * dr - nr * di) * inv;   // Im(a_disc)
  }
  const float s  = sqrtf(DT_F);
  const float cr = s * dr * inv;
  const float ci = -s * di * inv;
  for (int d = tid; d < DD; d += 256) {
    const float b = B[(size_t)n * DD + d];
    W[(size_t)n * DD + d]        = f2bf(b * cr);
    W[(size_t)(NS + n) * DD + d] = f2bf(b * ci);
  }
}

// ---------------------------------------------------------------------------
// gemm1 (R3 form): Bu[32768 x 256] bf16 = cvt(u[32768 x 1024]) * W[256 x 1024]^T
// 128x128 tile, 4 waves, BK=64, single-buffered LDS, glds for B, reg-cvt for A.
// XCD-chunked 1D grid (512 blocks).
// ---------------------------------------------------------------------------
__global__ __launch_bounds__(256) void gemm1(const float* __restrict__ U,
                                             const unsigned short* __restrict__ Bw,
                                             unsigned short* __restrict__ Bu) {
  __shared__ __align__(16) unsigned short As[128 * 64];
  __shared__ __align__(16) unsigned short Bs[128 * 64];
  const int tid  = threadIdx.x;
  const int lane = tid & 63;
  const int wave = tid >> 6;

  const int L   = blockIdx.x;
  const int xcd = L & 7;
  const int k   = L >> 3;              // 0..63 per XCD
  const int bm  = xcd * 32 + (k >> 1);
  const int bn  = k & 1;
  const int rowA0 = bm * 128, colB0 = bn * 128;
  const int wm = (wave >> 1) * 64, wn = (wave & 1) * 64;

  f32x4 acc[4][4];
  const f32x4 zero = {0.f, 0.f, 0.f, 0.f};
#pragma unroll
  for (int i = 0; i < 4; ++i)
#pragma unroll
    for (int j = 0; j < 4; ++j) acc[i][j] = zero;

  const int srow = tid >> 3;           // 0..31
  const int scol = (tid & 7) * 8;      // 0..56
  const int grow = wave * 8 + (lane >> 3);
  const int gcol = (lane & 7) * 8;

  for (int k0 = 0; k0 < DD; k0 += 64) {
    __syncthreads();
#pragma unroll
    for (int it = 0; it < 4; ++it) {
      const unsigned short* gb = Bw + (size_t)(colB0 + it * 32 + grow) * DD + k0 + gcol;
      __builtin_amdgcn_global_load_lds(AS1(gb), AS3(&Bs[(it * 32 + wave * 8) * 64]), 16, 0, 0);
    }
#pragma unroll
    for (int it = 0; it < 4; ++it) {
      const int r = it * 32 + srow;
      const float* ga = U + (size_t)(rowA0 + r) * DD + k0 + scol;
      fl4 v0 = *(const fl4*)ga;
      fl4 v1 = *(const fl4*)(ga + 4);
      bf16x8 pk;
#pragma unroll
      for (int e = 0; e < 4; ++e) { pk[e] = (short)f2bf_hw(v0[e]); pk[4 + e] = (short)f2bf_hw(v1[e]); }
      *(bf16x8*)&As[r * 64 + scol] = pk;
    }
    __syncthreads();
#pragma unroll
    for (int ks = 0; ks < 2; ++ks) {
      bf16x8 af[4], bfr[4];
#pragma unroll
      for (int i = 0; i < 4; ++i)
        af[i] = *(const bf16x8*)&As[(wm + i * 16 + (lane & 15)) * 64 + ks * 32 + (lane >> 4) * 8];
#pragma unroll
      for (int j = 0; j < 4; ++j)
        bfr[j] = *(const bf16x8*)&Bs[(wn + j * 16 + (lane & 15)) * 64 + ks * 32 + (lane >> 4) * 8];
#pragma unroll
      for (int i = 0; i < 4; ++i)
#pragma unroll
        for (int j = 0; j < 4; ++j)
          acc[i][j] = __builtin_amdgcn_mfma_f32_16x16x32_bf16(af[i], bfr[j], acc[i][j], 0, 0, 0);
    }
  }

  // C/D layout: col = lane&15, row = (lane>>4)*4 + q
#pragma unroll
  for (int i = 0; i < 4; ++i) {
    const int r0 = rowA0 + wm + i * 16 + (lane >> 4) * 4;
#pragma unroll
    for (int j = 0; j < 4; ++j) {
      const int c = colB0 + wn + j * 16 + (lane & 15);
#pragma unroll
      for (int q = 0; q < 4; ++q)
        Bu[(size_t)(r0 + q) * 256 + c] = f2bf_hw(acc[i][j][q]);
    }
  }
}

// ---------------------------------------------------------------------------
// scan_finals: per (b, chunk) local complex scan (h0=0) over bf16 Bu;
// writes chunk-final h (f32) to F. grid (NCH, NB), 128 threads.
// ---------------------------------------------------------------------------
__global__ void scan_finals(const unsigned short* __restrict__ Bu,
                            const float* __restrict__ ad, float* __restrict__ F) {
  const int c = blockIdx.x, b = blockIdx.y;
  const int n = threadIdx.x;
  const float ar = ad[n], ai = ad[NS + n];
  float hr = 0.f, hi = 0.f;
  const unsigned short* p = Bu + ((size_t)b * T_SEQ + (size_t)c * CHUNK) * 256;
#pragma unroll 8
  for (int t = 0; t < CHUNK; ++t) {
    const float br = bf2f(p[t * 256 + n]);
    const float bi = bf2f(p[t * 256 + 128 + n]);
    const float nr = fmaf(ar, hr, fmaf(-ai, hi, br));
    const float ni = fmaf(ar, hi, fmaf(ai, hr, bi));
    hr = nr; hi = ni;
  }
  F[((size_t)b * NCH + c) * 256 + n]       = hr;
  F[((size_t)b * NCH + c) * 256 + 128 + n] = hi;
}

// ---------------------------------------------------------------------------
// gemm2s: fused scan_apply + output GEMM.
// Block (b,c): fold carry from F[0..c-1], scan 64 steps from raw Bu seeded by
// carry (threads 0..127), write Re(h) bf16 into XOR-swizzled LDS tile
// (64 t-rows x 128 n-cols); then 4 waves compute y[64 x 1024] = h * Cb^T,
// Cb B-fragments loaded directly from global (L2-hot, 256 KB total).
// ---------------------------------------------------------------------------
__global__ __launch_bounds__(256) void gemm2s(const unsigned short* __restrict__ Bu,
                                              const float* __restrict__ F,
                                              const float* __restrict__ ad,
                                              const unsigned short* __restrict__ Cb,
                                              float* __restrict__ y) {
  __shared__ __align__(16) unsigned short Hl[64 * 128];   // swizzled Re(h)
  const int tid  = threadIdx.x;
  const int lane = tid & 63;
  const int wave = tid >> 6;
  const int L = blockIdx.x;            // 512 = NB * NCH
  const int b = L >> 5;                // /NCH
  const int c = L & 31;

  // ---- phase 1: carry-fold + local scan (threads 0..127, one per n) ----
  if (tid < 128) {
    const int n = tid;
    const float ar = ad[n], ai = ad[NS + n];
    float alr = ar, ali = ai;          // a^CHUNK (log2(64)=6 squarings)
#pragma unroll
    for (int s = 0; s < 6; ++s) {
      const float tr = alr * alr - ali * ali;
      const float ti = 2.f * alr * ali;
      alr = tr; ali = ti;
    }
    float hr = 0.f, hi = 0.f;          // carry = h at end of chunk c-1
    for (int cc = 0; cc < c; ++cc) {
      const float fr = F[((size_t)b * NCH + cc) * 256 + n];
      const float fi = F[((size_t)b * NCH + cc) * 256 + 128 + n];
      const float nr = fmaf(alr, hr, fmaf(-ali, hi, fr));
      const float ni = fmaf(alr, hi, fmaf(ali, hr, fi));
      hr = nr; hi = ni;
    }
    const unsigned short* p = Bu + ((size_t)b * T_SEQ + (size_t)c * CHUNK) * 256;
#pragma unroll 8
    for (int t = 0; t < CHUNK; ++t) {
      const float br = bf2f(p[t * 256 + n]);
      const float bi = bf2f(p[t * 256 + 128 + n]);
      const float nr = fmaf(ar, hr, fmaf(-ai, hi, br));
      const float ni = fmaf(ar, hi, fmaf(ai, hr, bi));
      hr = nr; hi = ni;
      // swizzled store: byte = t*256 + ((n*2) ^ ((t&7)<<4))
      const int byte = t * 256 + ((n * 2) ^ ((t & 7) << 4));
      *(unsigned short*)((char*)Hl + byte) = f2bf(hr);
    }
  }
  __syncthreads();

  // ---- phase 2: y[64 x 1024] = Hl(64x128) * Cb(1024x128)^T ----
  const size_t row0 = (size_t)b * T_SEQ + (size_t)c * CHUNK;
#pragma unroll
  for (int cg = 0; cg < 4; ++cg) {
    const int d0 = wave * 256 + cg * 64;
    f32x4 acc[4][4];
    const f32x4 zero = {0.f, 0.f, 0.f, 0.f};
#pragma unroll
    for (int i = 0; i < 4; ++i)
#pragma unroll
      for (int j = 0; j < 4; ++j) acc[i][j] = zero;

#pragma unroll
    for (int ks = 0; ks < 4; ++ks) {
      bf16x8 af[4], bfr[4];
#pragma unroll
      for (int i = 0; i < 4; ++i) {
        const int r = i * 16 + (lane & 15);
        const int byte = r * 256 + ((ks * 64 + (lane >> 4) * 16) ^ ((r & 7) << 4));
        af[i] = *(const bf16x8*)((const char*)Hl + byte);
      }
#pragma unroll
      for (int j = 0; j < 4; ++j) {
        const unsigned short* gb = Cb + (size_t)(d0 + j * 16 + (lane & 15)) * NS + ks * 32 + (lane >> 4) * 8;
        bfr[j] = *(const bf16x8*)gb;
      }
#pragma unroll
      for (int i = 0; i < 4; ++i)
#pragma unroll
        for (int j = 0; j < 4; ++j)
          acc[i][j] = __builtin_amdgcn_mfma_f32_16x16x32_bf16(af[i], bfr[j], acc[i][j], 0, 0, 0);
    }

#pragma unroll
    for (int i = 0; i < 4; ++i) {
      const size_t r0 = row0 + i * 16 + (lane >> 4) * 4;
#pragma unroll
      for (int j = 0; j < 4; ++j) {
        const int d = d0 + j * 16 + (lane & 15);
#pragma unroll
        for (int q = 0; q < 4; ++q)
          y[(r0 + q) * DD + d] = acc[i][j][q];
      }
    }
  }
}

// ---------------------------------------------------------------------------
extern "C" void kernel_launch(void* const* d_in, const int* in_sizes, int n_in,
                              void* d_out, int out_size, void* d_ws, size_t ws_size,
                              hipStream_t stream) {
  const float* u  = (const float*)d_in[0];
  const float* Ar = (const float*)d_in[1];
  const float* Ai = (const float*)d_in[2];
  const float* B  = (const float*)d_in[3];
  const float* C  = (const float*)d_in[4];
  float* y = (float*)d_out;
  char* ws = (char*)d_ws;

  // workspace layout (~18.5 MB)
  unsigned short* W  = (unsigned short*)(ws);                          // 512 KB (B_disc bf16)
  unsigned short* Cb = (unsigned short*)(ws + (512 << 10));            // 256 KB (C bf16)
  float*          ad = (float*)(ws + (768 << 10));                     // 1 KB   (a_disc)
  unsigned short* Bu = (unsigned short*)(ws + (1 << 20));              // 16.75 MB (complex bf16 Bu)
  float*          F  = (float*)(ws + (1 << 20) + 16777216);            // 512 KB (chunk finals f32)

  prep_all<<<dim3(640), dim3(256), 0, stream>>>(Ar, Ai, B, C, W, Cb, ad);
  gemm1<<<dim3(512), dim3(256), 0, stream>>>(u, W, Bu);
  scan_finals<<<dim3(NCH, NB), dim3(128), 0, stream>>>(Bu, ad, F);
  gemm2s<<<dim3(NB * NCH), dim3(256), 0, stream>>>(Bu, F, ad, Cb, y);
}

// Round 7
// 84.018 us; speedup vs baseline: 1.3963x; 1.0702x over previous
//
#include <hip/hip_runtime.h>
#include <hip/hip_bf16.h>
#include <cstdint>

#define DT_F    0.01f
#define NB      16      // batch
#define T_SEQ   2048    // sequence
#define DD      1024    // d_in
#define NS      128     // n_state
#define CHUNK   64      // rows per chunk / scan length
#define NCH     32      // chunks per batch

using f32x4  = __attribute__((ext_vector_type(4))) float;
using bf16x8 = __attribute__((ext_vector_type(8))) short;
using fl4    = __attribute__((ext_vector_type(4))) float;

#define AS1(p) ((const __attribute__((address_space(1))) void*)(p))
#define AS3(p) ((__attribute__((address_space(3))) void*)(p))

__device__ __forceinline__ unsigned short f2bf(float f) {
  union { float f; unsigned u; } v; v.f = f;
  unsigned r = v.u + 0x7fffu + ((v.u >> 16) & 1u);   // RNE
  return (unsigned short)(r >> 16);
}
__device__ __forceinline__ float bf2f(unsigned short s) {
  union { unsigned u; float f; } v; v.u = ((unsigned)s) << 16;
  return v.f;
}
__device__ __forceinline__ unsigned short f2bf_hw(float f) {
  __hip_bfloat16 h = __float2bfloat16(f);
  return __builtin_bit_cast(unsigned short, h);
}

// a_disc from raw A (per n), recomputed where needed (cheap, removes a buffer)
__device__ __forceinline__ void adisc(float Arn, float Ain, float& ar, float& ai) {
  const float dr = 1.f - 0.5f * DT_F * Arn;
  const float di = -0.5f * DT_F * Ain;
  const float inv = 1.f / (dr * dr + di * di);
  const float nr = 1.f + 0.5f * DT_F * Arn;
  const float nim = 0.5f * DT_F * Ain;
  ar = (nr * dr + nim * di) * inv;
  ai = (nim * dr - nr * di) * inv;
}

// ---------------------------------------------------------------------------
// prep_all: blocks 0..511 convert C->bf16; blocks 512..639 build B_disc rows.
// ---------------------------------------------------------------------------
__global__ void prep_all(const float* __restrict__ Ar, const float* __restrict__ Ai,
                         const float* __restrict__ B, const float* __restrict__ C,
                         unsigned short* __restrict__ W, unsigned short* __restrict__ Cb) {
  const int blk = blockIdx.x;
  const int tid = threadIdx.x;
  if (blk < 512) {
    const int i = blk * 256 + tid;
    Cb[i] = f2bf(C[i]);
    return;
  }
  const int n = blk - 512;
  const float ar = Ar[n], ai = Ai[n];
  const float dr = 1.f - 0.5f * DT_F * ar;
  const float di = -0.5f * DT_F * ai;
  const float inv = 1.f / (dr * dr + di * di);
  const float s  = sqrtf(DT_F);
  const float cr = s * dr * inv;
  const float ci = -s * di * inv;
  for (int d = tid; d < DD; d += 256) {
    const float b = B[(size_t)n * DD + d];
    W[(size_t)n * DD + d]        = f2bf(b * cr);
    W[(size_t)(NS + n) * DD + d] = f2bf(b * ci);
  }
}

// ---------------------------------------------------------------------------
// gemm1s: per chunk (blk = b*NCH + c, rows m in [blk*64, +64)):
//   Bu_tile[64 x 256] = cvt(u) * W^T   (BK=64, 16 K-steps, wave w owns cols
//   w*64..w*64+63); epilogue: acc -> swizzled LDS tile (re cc<128 at bytes
//   0..255 of each 512B row, im at 256..511); 128 threads run the 64-step
//   local scan (h0=0): Re(h_t) bf16 -> global Hs (linear [blk][t][n]),
//   complex chunk-final -> F.
// ---------------------------------------------------------------------------
__global__ __launch_bounds__(256, 2) void gemm1s(const float* __restrict__ U,
                                                 const float* __restrict__ Ar,
                                                 const float* __restrict__ Ai,
                                                 const unsigned short* __restrict__ W,
                                                 unsigned short* __restrict__ Hs,
                                                 float* __restrict__ F) {
  __shared__ __align__(16) char smem[40960];
  unsigned short* As = (unsigned short*)smem;            // [64][64]   8 KB
  unsigned short* Bs = (unsigned short*)(smem + 8192);   // [256][64] 32 KB
  char*           Bt = smem;                             // 64 rows x 512 B swizzled (epilogue)

  const int tid  = threadIdx.x;
  const int lane = tid & 63;
  const int wave = tid >> 6;
  const int blk  = blockIdx.x;
  const size_t m0 = (size_t)blk * CHUNK;

  f32x4 acc[4][4];
  const f32x4 zero = {0.f, 0.f, 0.f, 0.f};
#pragma unroll
  for (int i = 0; i < 4; ++i)
#pragma unroll
    for (int j = 0; j < 4; ++j) acc[i][j] = zero;

  const int srow  = tid >> 2;           // 0..63
  const int scol  = (tid & 3) * 16;     // 0..48
  const int growl = lane >> 3;          // 0..7
  const int gcol  = (lane & 7) * 8;

  for (int k0 = 0; k0 < DD; k0 += 64) {
    __syncthreads();
    // B stage: W rows [wave*64, +64), 8 glds per wave (8 rows / 1 KB each)
#pragma unroll
    for (int g = 0; g < 8; ++g) {
      const int row = wave * 64 + g * 8;
      const unsigned short* gb = W + (size_t)(row + growl) * DD + k0 + gcol;
      __builtin_amdgcn_global_load_lds(AS1(gb), AS3(&Bs[row * 64]), 16, 0, 0);
    }
    // A stage: 64x64 f32 -> bf16
    {
      const float* ga = U + (m0 + srow) * DD + k0 + scol;
      fl4 v0 = *(const fl4*)ga;
      fl4 v1 = *(const fl4*)(ga + 4);
      fl4 v2 = *(const fl4*)(ga + 8);
      fl4 v3 = *(const fl4*)(ga + 12);
      bf16x8 p0, p1;
#pragma unroll
      for (int e = 0; e < 4; ++e) {
        p0[e] = (short)f2bf_hw(v0[e]); p0[4 + e] = (short)f2bf_hw(v1[e]);
        p1[e] = (short)f2bf_hw(v2[e]); p1[4 + e] = (short)f2bf_hw(v3[e]);
      }
      *(bf16x8*)&As[srow * 64 + scol]     = p0;
      *(bf16x8*)&As[srow * 64 + scol + 8] = p1;
    }
    __syncthreads();
#pragma unroll
    for (int ks = 0; ks < 2; ++ks) {
      bf16x8 af[4], bfr[4];
#pragma unroll
      for (int i = 0; i < 4; ++i)
        af[i] = *(const bf16x8*)&As[(i * 16 + (lane & 15)) * 64 + ks * 32 + (lane >> 4) * 8];
#pragma unroll
      for (int j = 0; j < 4; ++j)
        bfr[j] = *(const bf16x8*)&Bs[(wave * 64 + j * 16 + (lane & 15)) * 64 + ks * 32 + (lane >> 4) * 8];
#pragma unroll
      for (int i = 0; i < 4; ++i)
#pragma unroll
        for (int j = 0; j < 4; ++j)
          acc[i][j] = __builtin_amdgcn_mfma_f32_16x16x32_bf16(af[i], bfr[j], acc[i][j], 0, 0, 0);
    }
  }
  __syncthreads();   // MFMA LDS reads done before Bt overwrites As/Bs

  // epilogue: acc -> swizzled Bt. byte(t, cc) = t*512 + ((cc*2) ^ ((t&7)<<4))
#pragma unroll
  for (int i = 0; i < 4; ++i) {
#pragma unroll
    for (int j = 0; j < 4; ++j) {
      const int cc = wave * 64 + j * 16 + (lane & 15);
#pragma unroll
      for (int q = 0; q < 4; ++q) {
        const int t = i * 16 + (lane >> 4) * 4 + q;
        *(unsigned short*)(Bt + t * 512 + ((cc * 2) ^ ((t & 7) << 4))) = f2bf_hw(acc[i][j][q]);
      }
    }
  }
  __syncthreads();

  // local scan (threads 0..127, one per n); Re(h) bf16 -> Hs; finals -> F
  if (tid < 128) {
    const int n = tid;
    float ar, ai; adisc(Ar[n], Ai[n], ar, ai);
    float hr = 0.f, hi = 0.f;
    unsigned short* o = Hs + (size_t)blk * (CHUNK * NS) + n;
#pragma unroll 8
    for (int t = 0; t < CHUNK; ++t) {
      const int reByte = t * 512 + ((n * 2) ^ ((t & 7) << 4));
      const float br = bf2f(*(const unsigned short*)(Bt + reByte));
      const float bi = bf2f(*(const unsigned short*)(Bt + reByte + 256));
      const float xr = fmaf(ar, hr, fmaf(-ai, hi, br));
      const float xi = fmaf(ar, hi, fmaf(ai, hr, bi));
      hr = xr; hi = xi;
      o[t * NS] = f2bf(hr);
    }
    F[(size_t)blk * 256 + n]       = hr;
    F[(size_t)blk * 256 + 128 + n] = hi;
  }
}

// ---------------------------------------------------------------------------
// gemm2s: per chunk blk: glds-load Hs tile with inverse-swizzled per-lane
// SOURCE addresses (LDS ends up in the swizzled layout); fold predecessor
// finals into carry; add Re(a^{t+1}*carry) in-LDS; GEMM2
// y[64 x 1024] = Hl * Cb^T  (A from swizzled LDS, Cb from L2-hot global).
// ---------------------------------------------------------------------------
__global__ __launch_bounds__(256, 2) void gemm2s(const unsigned short* __restrict__ Hs,
                                                 const float* __restrict__ F,
                                                 const float* __restrict__ Ar,
                                                 const float* __restrict__ Ai,
                                                 const unsigned short* __restrict__ Cb,
                                                 float* __restrict__ y) {
  __shared__ __align__(16) char Hl[64 * 256];   // 16 KB swizzled Re(h)
  const int tid  = threadIdx.x;
  const int lane = tid & 63;
  const int wave = tid >> 6;
  const int blk  = blockIdx.x;
  const int c    = blk & 31;
  const size_t m0 = (size_t)blk * CHUNK;

  // stage: LDS byte t*256 + X  <-  global tile byte t*256 + (X ^ ((t&7)<<4))
  const char* tile = (const char*)Hs + (size_t)blk * (CHUNK * NS * 2);
#pragma unroll
  for (int g = 0; g < 4; ++g) {
    const int r0 = wave * 16 + g * 4;
    const int r  = r0 + (lane >> 4);
    const int srcOff = r * 256 + ((((lane & 15)) * 16) ^ ((r & 7) << 4));
    __builtin_amdgcn_global_load_lds(AS1(tile + srcOff), AS3(Hl + r0 * 256), 16, 0, 0);
  }
  __syncthreads();

  // carry fold + in-LDS correction (threads 0..127)
  if (tid < 128) {
    const int n = tid;
    float ar, ai; adisc(Ar[n], Ai[n], ar, ai);
    if (c != 0) {
      float alr = ar, ali = ai;                 // a^CHUNK (2^6)
#pragma unroll
      for (int s = 0; s < 6; ++s) {
        const float tr = alr * alr - ali * ali;
        const float ti = 2.f * alr * ali;
        alr = tr; ali = ti;
      }
      float cr = 0.f, ci = 0.f;                 // carry = h at end of chunk c-1
      const float* Fb = F + (size_t)(blk - c) * 256;
      for (int cc = 0; cc < c; ++cc) {
        const float fr = Fb[(size_t)cc * 256 + n];
        const float fi = Fb[(size_t)cc * 256 + 128 + n];
        const float xr = fmaf(alr, cr, fmaf(-ali, ci, fr));
        const float xi = fmaf(alr, ci, fmaf(ali, cr, fi));
        cr = xr; ci = xi;
      }
      float gr = ar * cr - ai * ci;             // g_t = a^{t+1} * carry
      float gi = ar * ci + ai * cr;
#pragma unroll 8
      for (int t = 0; t < CHUNK; ++t) {
        unsigned short* pp = (unsigned short*)(Hl + t * 256 + ((n * 2) ^ ((t & 7) << 4)));
        *pp = f2bf(bf2f(*pp) + gr);
        const float xr = ar * gr - ai * gi;
        const float xi = ar * gi + ai * gr;
        gr = xr; gi = xi;
      }
    }
  }
  __syncthreads();

  // GEMM2: y[64 x 1024] = Hl(64x128 swizzled) * Cb(1024x128)^T
  const f32x4 zero = {0.f, 0.f, 0.f, 0.f};
#pragma unroll
  for (int cg = 0; cg < 4; ++cg) {
    const int d0 = wave * 256 + cg * 64;
    f32x4 oacc[4][4];
#pragma unroll
    for (int i = 0; i < 4; ++i)
#pragma unroll
      for (int j = 0; j < 4; ++j) oacc[i][j] = zero;

#pragma unroll
    for (int ks = 0; ks < 4; ++ks) {
      bf16x8 af[4], bfr[4];
#pragma unroll
      for (int i = 0; i < 4; ++i) {
        const int r = i * 16 + (lane & 15);
        af[i] = *(const bf16x8*)(Hl + r * 256 + ((ks * 64 + (lane >> 4) * 16) ^ ((r & 7) << 4)));
      }
#pragma unroll
      for (int j = 0; j < 4; ++j)
        bfr[j] = *(const bf16x8*)(Cb + (size_t)(d0 + j * 16 + (lane & 15)) * NS + ks * 32 + (lane >> 4) * 8);
#pragma unroll
      for (int i = 0; i < 4; ++i)
#pragma unroll
        for (int j = 0; j < 4; ++j)
          oacc[i][j] = __builtin_amdgcn_mfma_f32_16x16x32_bf16(af[i], bfr[j], oacc[i][j], 0, 0, 0);
    }
#pragma unroll
    for (int i = 0; i < 4; ++i) {
      const size_t r0 = m0 + i * 16 + (lane >> 4) * 4;
#pragma unroll
      for (int j = 0; j < 4; ++j) {
        const int d = d0 + j * 16 + (lane & 15);
#pragma unroll
        for (int q = 0; q < 4; ++q)
          y[(r0 + q) * DD + d] = oacc[i][j][q];
      }
    }
  }
}

// ---------------------------------------------------------------------------
extern "C" void kernel_launch(void* const* d_in, const int* in_sizes, int n_in,
                              void* d_out, int out_size, void* d_ws, size_t ws_size,
                              hipStream_t stream) {
  const float* u  = (const float*)d_in[0];
  const float* Ar = (const float*)d_in[1];
  const float* Ai = (const float*)d_in[2];
  const float* B  = (const float*)d_in[3];
  const float* C  = (const float*)d_in[4];
  float* y = (float*)d_out;
  char* ws = (char*)d_ws;

  unsigned short* W  = (unsigned short*)(ws);                  // 512 KB (B_disc bf16)
  unsigned short* Cb = (unsigned short*)(ws + (512 << 10));    // 256 KB (C bf16)
  float*          F  = (float*)(ws + (768 << 10));             // 512 KB (chunk finals f32)
  unsigned short* Hs = (unsigned short*)(ws + (1280 << 10));   // 8 MB   (Re(h_local) bf16)

  prep_all<<<dim3(640), dim3(256), 0, stream>>>(Ar, Ai, B, C, W, Cb);
  gemm1s<<<dim3(NB * NCH), dim3(256), 0, stream>>>(u, Ar, Ai, W, Hs, F);
  gemm2s<<<dim3(NB * NCH), dim3(256), 0, stream>>>(Hs, F, Ar, Ai, Cb, y);
}